// Round 1
// baseline (888.034 us; speedup 1.0000x reference)
//
#include <hip/hip_runtime.h>
#include <math.h>

#define NN 20000
#define EE 320000
#define DIN 256
#define DD 128
#define HHEADS 4
#define NCLS 7

// ---------------- CSR build ----------------
__global__ void count_kernel(const int* __restrict__ ei, int* __restrict__ deg_src,
                             int* __restrict__ cnt_dst) {
  int e = blockIdx.x * blockDim.x + threadIdx.x;
  if (e >= EE) return;
  atomicAdd(&deg_src[ei[e]], 1);
  atomicAdd(&cnt_dst[ei[EE + e]], 1);
}

__global__ void scan_kernel(const int* __restrict__ cnt, int* __restrict__ row_ptr) {
  __shared__ int smem[256];
  __shared__ int carry_s;
  if (threadIdx.x == 0) carry_s = 0;
  __syncthreads();
  for (int base = 0; base < NN; base += 256) {
    int i = base + threadIdx.x;
    int x = (i < NN) ? cnt[i] : 0;
    smem[threadIdx.x] = x;
    __syncthreads();
    for (int off = 1; off < 256; off <<= 1) {
      int t = (threadIdx.x >= off) ? smem[threadIdx.x - off] : 0;
      __syncthreads();
      smem[threadIdx.x] += t;
      __syncthreads();
    }
    int incl = smem[threadIdx.x];
    if (i < NN) row_ptr[i] = carry_s + incl - x;
    __syncthreads();
    if (threadIdx.x == 255) carry_s += smem[255];
    __syncthreads();
  }
  if (threadIdx.x == 0) row_ptr[NN] = EE;
}

__global__ void scatter_kernel(const int* __restrict__ ei, const int* __restrict__ row_ptr,
                               int* __restrict__ fill, int* __restrict__ ssrc) {
  int e = blockIdx.x * blockDim.x + threadIdx.x;
  if (e >= EE) return;
  int s = ei[e], d = ei[EE + e];
  int pos = row_ptr[d] + atomicAdd(&fill[d], 1);
  ssrc[pos] = s;
}

// ---------------- fp32 tiled GEMM: C[nrows x M] = A[nrows x K] @ B[K x M] + bias ----------------
__global__ __launch_bounds__(256) void sgemm_bias(
    const float* __restrict__ A, const float* __restrict__ B,
    const float* __restrict__ bias, float* __restrict__ C,
    int nrows, int K, int M) {
  __shared__ float As[16][64];  // As[k][row]
  __shared__ float Bs[16][64];  // Bs[k][col]
  const int tid = threadIdx.x;
  const int brow = blockIdx.x * 64;
  const int bcol = blockIdx.y * 64;
  const int ty = tid >> 4;   // 0..15 row group
  const int tx = tid & 15;   // 0..15 col group
  const int ar = tid >> 2;          // 0..63 (A row within tile)
  const int akc = (tid & 3) << 2;   // 0,4,8,12 (A k within tile)
  const int bkr = tid >> 4;         // 0..15 (B k row)
  const int bc4 = (tid & 15) << 2;  // 0..60 (B col)
  float acc[4][4] = {{0.f}};
  for (int k0 = 0; k0 < K; k0 += 16) {
    float4 av = make_float4(0.f, 0.f, 0.f, 0.f);
    int arow = brow + ar;
    if (arow < nrows) av = *reinterpret_cast<const float4*>(A + (size_t)arow * K + k0 + akc);
    As[akc + 0][ar] = av.x; As[akc + 1][ar] = av.y;
    As[akc + 2][ar] = av.z; As[akc + 3][ar] = av.w;
    float4 bv = *reinterpret_cast<const float4*>(B + (size_t)(k0 + bkr) * M + bcol + bc4);
    *reinterpret_cast<float4*>(&Bs[bkr][bc4]) = bv;
    __syncthreads();
#pragma unroll
    for (int kk = 0; kk < 16; ++kk) {
      float a0 = As[kk][ty * 4 + 0], a1 = As[kk][ty * 4 + 1];
      float a2 = As[kk][ty * 4 + 2], a3 = As[kk][ty * 4 + 3];
      float b0 = Bs[kk][tx * 4 + 0], b1 = Bs[kk][tx * 4 + 1];
      float b2 = Bs[kk][tx * 4 + 2], b3 = Bs[kk][tx * 4 + 3];
      acc[0][0] += a0 * b0; acc[0][1] += a0 * b1; acc[0][2] += a0 * b2; acc[0][3] += a0 * b3;
      acc[1][0] += a1 * b0; acc[1][1] += a1 * b1; acc[1][2] += a1 * b2; acc[1][3] += a1 * b3;
      acc[2][0] += a2 * b0; acc[2][1] += a2 * b1; acc[2][2] += a2 * b2; acc[2][3] += a2 * b3;
      acc[3][0] += a3 * b0; acc[3][1] += a3 * b1; acc[3][2] += a3 * b2; acc[3][3] += a3 * b3;
    }
    __syncthreads();
  }
#pragma unroll
  for (int ii = 0; ii < 4; ++ii) {
    int row = brow + ty * 4 + ii;
    if (row >= nrows) break;
    float* crow = C + (size_t)row * M + bcol + tx * 4;
    const float* bb = bias + bcol + tx * 4;
    crow[0] = acc[ii][0] + bb[0];
    crow[1] = acc[ii][1] + bb[1];
    crow[2] = acc[ii][2] + bb[2];
    crow[3] = acc[ii][3] + bb[3];
  }
}

// ---------------- degree positional encoding ----------------
__global__ void add_pe_kernel(float* __restrict__ h, const int* __restrict__ deg) {
  int idx = blockIdx.x * blockDim.x + threadIdx.x;
  if (idx >= NN * DD) return;
  int i = idx >> 7;
  int d = idx & 127;
  float dg = (float)deg[i];
  float freq = dg / powf(10000.0f, (float)d * (1.0f / 128.0f));
  float pe = (d & 1) ? cosf(freq) : sinf(freq);
  h[idx] += pe;
}

// ---------------- fused attention + head-mean + skip + residual + LN (+ReLU) ----------------
// one block (4 waves = 4 heads) per destination node
__global__ __launch_bounds__(256) void attn_fused(
    const float* __restrict__ h, const float* __restrict__ q, const float* __restrict__ k,
    const float* __restrict__ v, const float* __restrict__ skipb,
    const int* __restrict__ row_ptr, const int* __restrict__ ssrc,
    const float* __restrict__ ln_g, const float* __restrict__ ln_b,
    float* __restrict__ h_out, int relu_flag) {
  const int i = blockIdx.x;
  const int tid = threadIdx.x;
  const int hh = tid >> 6;   // head
  const int lane = tid & 63;
  const int d0 = lane * 2;
  const int e0 = row_ptr[i], e1 = row_ptr[i + 1];

  const float2 qv = *reinterpret_cast<const float2*>(q + (size_t)i * 512 + hh * 128 + d0);
  float m = -INFINITY, s = 0.f, a0 = 0.f, a1 = 0.f;
  for (int e = e0; e < e1; ++e) {
    int j = ssrc[e];
    const float2 kv = *reinterpret_cast<const float2*>(k + (size_t)j * 512 + hh * 128 + d0);
    float part = qv.x * kv.x + qv.y * kv.y;
#pragma unroll
    for (int off = 32; off; off >>= 1) part += __shfl_xor(part, off);
    float score = part * 0.088388347648318447f;  // 1/sqrt(128)
    const float2 vv = *reinterpret_cast<const float2*>(v + (size_t)j * 512 + hh * 128 + d0);
    float nm = fmaxf(m, score);
    float c = __expf(m - nm);
    float p = __expf(score - nm);
    s = s * c + p;
    a0 = a0 * c + p * vv.x;
    a1 = a1 * c + p * vv.y;
    m = nm;
  }
  float inv = 1.f / (s + 1e-16f);
  a0 *= inv; a1 *= inv;

  __shared__ float agg[HHEADS][DD];
  __shared__ float red[8];
  agg[hh][d0] = a0;
  agg[hh][d0 + 1] = a1;
  __syncthreads();

  float val = 0.f;
  const int d = tid;
  if (tid < DD) {
    float hmean = (agg[0][d] + agg[1][d] + agg[2][d] + agg[3][d]) * 0.25f;
    val = hmean + skipb[(size_t)i * DD + d] + h[(size_t)i * DD + d];
  }
  float sum = (tid < DD) ? val : 0.f;
  float sq = (tid < DD) ? val * val : 0.f;
#pragma unroll
  for (int off = 32; off; off >>= 1) {
    sum += __shfl_xor(sum, off);
    sq += __shfl_xor(sq, off);
  }
  if (lane == 0) { red[hh] = sum; red[4 + hh] = sq; }
  __syncthreads();
  float tot = red[0] + red[1] + red[2] + red[3];
  float tot2 = red[4] + red[5] + red[6] + red[7];
  float mu = tot * (1.f / 128.f);
  float var = tot2 * (1.f / 128.f) - mu * mu;
  float rstd = rsqrtf(var + 1e-5f);
  if (tid < DD) {
    float y = (val - mu) * rstd * ln_g[d] + ln_b[d];
    if (relu_flag) y = fmaxf(y, 0.f);
    h_out[(size_t)i * DD + d] = y;
  }
}

// ---------------- classifier: out[N x 7] = h @ Wc + bc ----------------
__global__ __launch_bounds__(256) void out_gemm(const float* __restrict__ h,
                                                const float* __restrict__ Wc,
                                                const float* __restrict__ bc,
                                                float* __restrict__ out) {
  int node = blockIdx.x * 4 + (threadIdx.x >> 6);
  int lane = threadIdx.x & 63;
  if (node >= NN) return;
  const float2 hv = *reinterpret_cast<const float2*>(h + (size_t)node * DD + lane * 2);
#pragma unroll
  for (int c = 0; c < NCLS; ++c) {
    float p = hv.x * Wc[(lane * 2) * NCLS + c] + hv.y * Wc[(lane * 2 + 1) * NCLS + c];
#pragma unroll
    for (int off = 32; off; off >>= 1) p += __shfl_xor(p, off);
    if (lane == 0) out[(size_t)node * NCLS + c] = p + bc[c];
  }
}

extern "C" void kernel_launch(void* const* d_in, const int* in_sizes, int n_in,
                              void* d_out, int out_size, void* d_ws, size_t ws_size,
                              hipStream_t stream) {
  const float* x    = (const float*)d_in[0];
  const int*   ei   = (const int*)d_in[1];
  const float* W_in = (const float*)d_in[2];
  const float* b_in = (const float*)d_in[3];
  const float* Wq   = (const float*)d_in[4];
  const float* bq   = (const float*)d_in[5];
  const float* Wk   = (const float*)d_in[6];
  const float* bk   = (const float*)d_in[7];
  const float* Wv   = (const float*)d_in[8];
  const float* bv   = (const float*)d_in[9];
  const float* Wsk  = (const float*)d_in[10];
  const float* bsk  = (const float*)d_in[11];
  const float* ln_g = (const float*)d_in[12];
  const float* ln_b = (const float*)d_in[13];
  const float* Wc   = (const float*)d_in[14];
  const float* bc   = (const float*)d_in[15];
  float* out = (float*)d_out;

  char* ws = (char*)d_ws;
  size_t off = 0;
  float* h     = (float*)(ws + off); off += (size_t)NN * DD * 4;
  float* qb    = (float*)(ws + off); off += (size_t)NN * HHEADS * DD * 4;
  float* kb    = (float*)(ws + off); off += (size_t)NN * HHEADS * DD * 4;
  float* vb    = (float*)(ws + off); off += (size_t)NN * HHEADS * DD * 4;
  float* skipb = (float*)(ws + off); off += (size_t)NN * DD * 4;
  int* deg     = (int*)(ws + off); off += (size_t)NN * 4;
  int* cnt     = (int*)(ws + off); off += (size_t)NN * 4;
  int* fill    = (int*)(ws + off); off += (size_t)NN * 4;
  int* row_ptr = (int*)(ws + off); off += (size_t)(NN + 1) * 4;
  int* ssrc    = (int*)(ws + off); off += (size_t)EE * 4;

  // zero deg/cnt/fill (contiguous)
  hipMemsetAsync(deg, 0, (size_t)NN * 3 * 4, stream);

  count_kernel<<<(EE + 255) / 256, 256, 0, stream>>>(ei, deg, cnt);
  scan_kernel<<<1, 256, 0, stream>>>(cnt, row_ptr);
  scatter_kernel<<<(EE + 255) / 256, 256, 0, stream>>>(ei, row_ptr, fill, ssrc);

  // h0 = x @ W_in + b_in ; then += degree PE
  {
    dim3 grid((NN + 63) / 64, DD / 64);
    sgemm_bias<<<grid, 256, 0, stream>>>(x, W_in, b_in, h, NN, DIN, DD);
  }
  add_pe_kernel<<<(NN * DD + 255) / 256, 256, 0, stream>>>(h, deg);

  for (int l = 0; l < 2; ++l) {
    const float* Wql = Wq + (size_t)l * DD * HHEADS * DD;
    const float* bql = bq + (size_t)l * HHEADS * DD;
    const float* Wkl = Wk + (size_t)l * DD * HHEADS * DD;
    const float* bkl = bk + (size_t)l * HHEADS * DD;
    const float* Wvl = Wv + (size_t)l * DD * HHEADS * DD;
    const float* bvl = bv + (size_t)l * HHEADS * DD;
    const float* Wsl = Wsk + (size_t)l * DD * DD;
    const float* bsl = bsk + (size_t)l * DD;

    dim3 gqkv((NN + 63) / 64, (HHEADS * DD) / 64);
    sgemm_bias<<<gqkv, 256, 0, stream>>>(h, Wql, bql, qb, NN, DD, HHEADS * DD);
    sgemm_bias<<<gqkv, 256, 0, stream>>>(h, Wkl, bkl, kb, NN, DD, HHEADS * DD);
    sgemm_bias<<<gqkv, 256, 0, stream>>>(h, Wvl, bvl, vb, NN, DD, HHEADS * DD);
    dim3 gsk((NN + 63) / 64, DD / 64);
    sgemm_bias<<<gsk, 256, 0, stream>>>(h, Wsl, bsl, skipb, NN, DD, DD);

    attn_fused<<<NN, 256, 0, stream>>>(h, qb, kb, vb, skipb, row_ptr, ssrc,
                                       ln_g + (size_t)l * DD, ln_b + (size_t)l * DD,
                                       h, (l == 0) ? 1 : 0);
  }

  out_gemm<<<NN / 4, 256, 0, stream>>>(h, Wc, bc, out);
}

// Round 3
// 511.377 us; speedup vs baseline: 1.7366x; 1.7366x over previous
//
#include <hip/hip_runtime.h>
#include <math.h>

#define NN 20000
#define EE 320000
#define DIN 256
#define DD 128
#define HHEADS 4
#define NCLS 7

typedef __attribute__((ext_vector_type(8))) __bf16 bf16x8;
typedef __attribute__((ext_vector_type(4))) float f32x4;

__device__ __forceinline__ unsigned short f2bf(float f) {
  union { float f; unsigned int u; } c; c.f = f;
  unsigned int r = c.u + 0x7fffu + ((c.u >> 16) & 1u);  // RNE
  return (unsigned short)(r >> 16);
}
__device__ __forceinline__ float bf_lo(unsigned int u) {
  union { unsigned int x; float f; } c; c.x = u << 16; return c.f;
}
__device__ __forceinline__ float bf_hi(unsigned int u) {
  union { unsigned int x; float f; } c; c.x = u & 0xffff0000u; return c.f;
}

// ---------------- utility: zero / copy int buffers (plain kernels; no memset nodes) ----------------
__global__ void zero_ints(int* __restrict__ p, int n) {
  int i = blockIdx.x * blockDim.x + threadIdx.x;
  if (i < n) p[i] = 0;
}
__global__ void copy_ints(const int* __restrict__ src, int* __restrict__ dst, int n) {
  int i = blockIdx.x * blockDim.x + threadIdx.x;
  if (i < n) dst[i] = src[i];
}

// ---------------- CSR build ----------------
__global__ void count_kernel(const int* __restrict__ ei, int* __restrict__ deg_src,
                             int* __restrict__ cnt_dst) {
  int e = blockIdx.x * blockDim.x + threadIdx.x;
  if (e >= EE) return;
  atomicAdd(&deg_src[ei[e]], 1);
  atomicAdd(&cnt_dst[ei[EE + e]], 1);
}

__global__ void scan_kernel(const int* __restrict__ cnt, int* __restrict__ row_ptr) {
  __shared__ int smem[256];
  __shared__ int carry_s;
  if (threadIdx.x == 0) carry_s = 0;
  __syncthreads();
  for (int base = 0; base < NN; base += 256) {
    int i = base + threadIdx.x;
    int x = (i < NN) ? cnt[i] : 0;
    smem[threadIdx.x] = x;
    __syncthreads();
    for (int off = 1; off < 256; off <<= 1) {
      int t = (threadIdx.x >= off) ? smem[threadIdx.x - off] : 0;
      __syncthreads();
      smem[threadIdx.x] += t;
      __syncthreads();
    }
    int incl = smem[threadIdx.x];
    if (i < NN) row_ptr[i] = carry_s + incl - x;
    __syncthreads();
    if (threadIdx.x == 255) carry_s += smem[255];
    __syncthreads();
  }
  if (threadIdx.x == 0) row_ptr[NN] = EE;
}

// scatter: fillp was copied from row_ptr; atomicAdd gives the absolute slot
__global__ void scatter_kernel(const int* __restrict__ ei, int* __restrict__ fillp,
                               int* __restrict__ ssrc) {
  int e = blockIdx.x * blockDim.x + threadIdx.x;
  if (e >= EE) return;
  int s = ei[e], d = ei[EE + e];
  int pos = atomicAdd(&fillp[d], 1);
  ssrc[pos] = s;
}

// ---------------- pack all weights: fp32 [K][M] -> bf16 [M][K] ----------------
// WT layout (elements): W_inT @0 (32768), WqT @32768 (2*65536),
// WkT @163840, WvT @294912, WskT @425984 (2*16384); total 458752
__global__ void pack_weights(const float* __restrict__ W_in, const float* __restrict__ Wq,
                             const float* __restrict__ Wk, const float* __restrict__ Wv,
                             const float* __restrict__ Wsk, __bf16* __restrict__ WT) {
  int idx = blockIdx.x * blockDim.x + threadIdx.x;
  if (idx >= 458752) return;
  float val;
  if (idx < 32768) {                       // W_in: K=256, M=128
    int m = idx >> 8, k = idx & 255;
    val = W_in[k * 128 + m];
  } else if (idx < 163840) {               // Wq: K=128, M=512
    int t = idx - 32768; int l = t >> 16, r = t & 65535, m = r >> 7, k = r & 127;
    val = Wq[l * 65536 + k * 512 + m];
  } else if (idx < 294912) {               // Wk
    int t = idx - 163840; int l = t >> 16, r = t & 65535, m = r >> 7, k = r & 127;
    val = Wk[l * 65536 + k * 512 + m];
  } else if (idx < 425984) {               // Wv
    int t = idx - 294912; int l = t >> 16, r = t & 65535, m = r >> 7, k = r & 127;
    val = Wv[l * 65536 + k * 512 + m];
  } else {                                 // Wskip: K=128, M=128
    int t = idx - 425984; int l = t >> 14, r = t & 16383, m = r >> 7, k = r & 127;
    val = Wsk[l * 16384 + k * 128 + m];
  }
  union { unsigned short u; __bf16 b; } cv; cv.u = f2bf(val);
  WT[idx] = cv.b;
}

// ---------------- fp32 -> bf16 convert (vector x4) ----------------
__global__ void cvt_f32_bf16(const float* __restrict__ in, __bf16* __restrict__ out, int n4) {
  int i = blockIdx.x * blockDim.x + threadIdx.x;
  if (i >= n4) return;
  float4 f = reinterpret_cast<const float4*>(in)[i];
  ushort4 u;
  u.x = f2bf(f.x); u.y = f2bf(f.y); u.z = f2bf(f.z); u.w = f2bf(f.w);
  reinterpret_cast<ushort4*>(out)[i] = u;
}

// ---------------- bf16 MFMA GEMM: C[nrows x M] = A @ B^T + bias ----------------
// A: bf16 [nrows][K]; BT: bf16 [M][K]; C: OutT
template <typename OutT>
__global__ __launch_bounds__(256) void mfma_gemm_bias(
    const __bf16* __restrict__ A, const __bf16* __restrict__ BT,
    const float* __restrict__ bias, OutT* __restrict__ C,
    int nrows, int K, int M) {
  __shared__ __attribute__((aligned(16))) __bf16 As[64][72];
  __shared__ __attribute__((aligned(16))) __bf16 Bs[64][72];
  const int tid = threadIdx.x;
  const int brow = blockIdx.x * 64;
  const int bcol = blockIdx.y * 64;
  const int wave = tid >> 6, lane = tid & 63;
  const int wm = wave & 1, wn = wave >> 1;
  const int r8 = tid >> 3;        // 0..31
  const int c8 = (tid & 7) * 8;   // 0..56
  const int lm = lane & 15, lk = (lane >> 4) * 8;
  f32x4 acc[2][2] = {};
  for (int k0 = 0; k0 < K; k0 += 64) {
#pragma unroll
    for (int half = 0; half < 2; ++half) {
      int row = brow + half * 32 + r8;
      uint4 av = make_uint4(0, 0, 0, 0);
      if (row < nrows) av = *reinterpret_cast<const uint4*>(A + (size_t)row * K + k0 + c8);
      *reinterpret_cast<uint4*>(&As[half * 32 + r8][c8]) = av;
      int col = bcol + half * 32 + r8;
      uint4 bv = *reinterpret_cast<const uint4*>(BT + (size_t)col * K + k0 + c8);
      *reinterpret_cast<uint4*>(&Bs[half * 32 + r8][c8]) = bv;
    }
    __syncthreads();
#pragma unroll
    for (int ks = 0; ks < 2; ++ks) {
      bf16x8 af[2], bfr[2];
#pragma unroll
      for (int i = 0; i < 2; ++i)
        af[i] = *reinterpret_cast<const bf16x8*>(&As[wm * 32 + i * 16 + lm][ks * 32 + lk]);
#pragma unroll
      for (int j = 0; j < 2; ++j)
        bfr[j] = *reinterpret_cast<const bf16x8*>(&Bs[wn * 32 + j * 16 + lm][ks * 32 + lk]);
#pragma unroll
      for (int i = 0; i < 2; ++i)
#pragma unroll
        for (int j = 0; j < 2; ++j)
          acc[i][j] = __builtin_amdgcn_mfma_f32_16x16x32_bf16(af[i], bfr[j], acc[i][j], 0, 0, 0);
    }
    __syncthreads();
  }
#pragma unroll
  for (int i = 0; i < 2; ++i) {
#pragma unroll
    for (int j = 0; j < 2; ++j) {
      int col = bcol + wn * 32 + j * 16 + lm;
      float bb = bias[col];
#pragma unroll
      for (int r = 0; r < 4; ++r) {
        int row = brow + wm * 32 + i * 16 + (lane >> 4) * 4 + r;
        if (row < nrows) {
          float v = acc[i][j][r] + bb;
          if constexpr (__is_same(OutT, float)) {
            C[(size_t)row * M + col] = v;
          } else {
            union { unsigned short u; __bf16 b; } cv; cv.u = f2bf(v);
            C[(size_t)row * M + col] = cv.b;
          }
        }
      }
    }
  }
}

// ---------------- degree positional encoding ----------------
__global__ void add_pe_kernel(float* __restrict__ h, const int* __restrict__ deg) {
  int idx = blockIdx.x * blockDim.x + threadIdx.x;
  if (idx >= NN * DD) return;
  int i = idx >> 7;
  int d = idx & 127;
  float dg = (float)deg[i];
  float freq = dg * __expf(-0.07195578415606394f * (float)d);  // 10000^(-d/128)
  float pe = (d & 1) ? cosf(freq) : sinf(freq);
  h[idx] += pe;
}

// ---------------- fused attention + head-mean + skip + residual + LN (+ReLU) ----------------
// h_in and h_out are DISTINCT buffers (ping-pong) — no in-place anywhere.
__global__ __launch_bounds__(256) void attn_fused(
    const float* __restrict__ h_in, const float* __restrict__ q,
    const __bf16* __restrict__ k, const __bf16* __restrict__ v,
    const float* __restrict__ skipb,
    const int* __restrict__ row_ptr, const int* __restrict__ ssrc,
    const float* __restrict__ ln_g, const float* __restrict__ ln_b,
    float* __restrict__ h_out, __bf16* __restrict__ hb_out, int relu_flag) {
  const int i = blockIdx.x;
  const int tid = threadIdx.x;
  const int hh = tid >> 6;
  const int lane = tid & 63;
  const int d0 = lane * 2;
  const int e0 = row_ptr[i], e1 = row_ptr[i + 1];
  const float scale = 0.088388347648318447f;  // 1/sqrt(128)

  const float2 qv = *reinterpret_cast<const float2*>(q + (size_t)i * 512 + hh * 128 + d0);
  float m = -INFINITY, s = 0.f, a0 = 0.f, a1 = 0.f;
  int e = e0;
  for (; e + 2 <= e1; e += 2) {
    int j0 = ssrc[e], j1 = ssrc[e + 1];
    unsigned int kw0 = *reinterpret_cast<const unsigned int*>(k + (size_t)j0 * 512 + hh * 128 + d0);
    unsigned int kw1 = *reinterpret_cast<const unsigned int*>(k + (size_t)j1 * 512 + hh * 128 + d0);
    float p0 = qv.x * bf_lo(kw0) + qv.y * bf_hi(kw0);
    float p1 = qv.x * bf_lo(kw1) + qv.y * bf_hi(kw1);
#pragma unroll
    for (int off = 32; off; off >>= 1) {
      p0 += __shfl_xor(p0, off);
      p1 += __shfl_xor(p1, off);
    }
    unsigned int vw0 = *reinterpret_cast<const unsigned int*>(v + (size_t)j0 * 512 + hh * 128 + d0);
    unsigned int vw1 = *reinterpret_cast<const unsigned int*>(v + (size_t)j1 * 512 + hh * 128 + d0);
    float sc0 = p0 * scale, sc1 = p1 * scale;
    float nm = fmaxf(m, fmaxf(sc0, sc1));
    float c = __expf(m - nm);
    float w0 = __expf(sc0 - nm), w1 = __expf(sc1 - nm);
    s = s * c + w0 + w1;
    a0 = a0 * c + w0 * bf_lo(vw0) + w1 * bf_lo(vw1);
    a1 = a1 * c + w0 * bf_hi(vw0) + w1 * bf_hi(vw1);
    m = nm;
  }
  if (e < e1) {
    int j0 = ssrc[e];
    unsigned int kw0 = *reinterpret_cast<const unsigned int*>(k + (size_t)j0 * 512 + hh * 128 + d0);
    float p0 = qv.x * bf_lo(kw0) + qv.y * bf_hi(kw0);
#pragma unroll
    for (int off = 32; off; off >>= 1) p0 += __shfl_xor(p0, off);
    unsigned int vw0 = *reinterpret_cast<const unsigned int*>(v + (size_t)j0 * 512 + hh * 128 + d0);
    float sc0 = p0 * scale;
    float nm = fmaxf(m, sc0);
    float c = __expf(m - nm);
    float w0 = __expf(sc0 - nm);
    s = s * c + w0;
    a0 = a0 * c + w0 * bf_lo(vw0);
    a1 = a1 * c + w0 * bf_hi(vw0);
    m = nm;
  }
  float inv = 1.f / (s + 1e-16f);
  a0 *= inv; a1 *= inv;

  __shared__ float agg[HHEADS][DD];
  __shared__ float red[8];
  agg[hh][d0] = a0;
  agg[hh][d0 + 1] = a1;
  __syncthreads();

  float val = 0.f;
  const int d = tid;
  if (tid < DD) {
    float hmean = (agg[0][d] + agg[1][d] + agg[2][d] + agg[3][d]) * 0.25f;
    val = hmean + skipb[(size_t)i * DD + d] + h_in[(size_t)i * DD + d];
  }
  float sum = (tid < DD) ? val : 0.f;
  float sq = (tid < DD) ? val * val : 0.f;
#pragma unroll
  for (int off = 32; off; off >>= 1) {
    sum += __shfl_xor(sum, off);
    sq += __shfl_xor(sq, off);
  }
  if (lane == 0) { red[hh] = sum; red[4 + hh] = sq; }
  __syncthreads();
  float tot = red[0] + red[1] + red[2] + red[3];
  float tot2 = red[4] + red[5] + red[6] + red[7];
  float mu = tot * (1.f / 128.f);
  float var = tot2 * (1.f / 128.f) - mu * mu;
  float rstd = rsqrtf(var + 1e-5f);
  if (tid < DD) {
    float y = (val - mu) * rstd * ln_g[d] + ln_b[d];
    if (relu_flag) y = fmaxf(y, 0.f);
    h_out[(size_t)i * DD + d] = y;
    union { unsigned short u; __bf16 b; } cv; cv.u = f2bf(y);
    hb_out[(size_t)i * DD + d] = cv.b;
  }
}

// ---------------- classifier: out[N x 7] = h @ Wc + bc ----------------
__global__ __launch_bounds__(256) void out_gemm(const float* __restrict__ h,
                                                const float* __restrict__ Wc,
                                                const float* __restrict__ bc,
                                                float* __restrict__ out) {
  int node = blockIdx.x * 4 + (threadIdx.x >> 6);
  int lane = threadIdx.x & 63;
  if (node >= NN) return;
  const float2 hv = *reinterpret_cast<const float2*>(h + (size_t)node * DD + lane * 2);
#pragma unroll
  for (int c = 0; c < NCLS; ++c) {
    float p = hv.x * Wc[(lane * 2) * NCLS + c] + hv.y * Wc[(lane * 2 + 1) * NCLS + c];
#pragma unroll
    for (int off = 32; off; off >>= 1) p += __shfl_xor(p, off);
    if (lane == 0) out[(size_t)node * NCLS + c] = p + bc[c];
  }
}

extern "C" void kernel_launch(void* const* d_in, const int* in_sizes, int n_in,
                              void* d_out, int out_size, void* d_ws, size_t ws_size,
                              hipStream_t stream) {
  const float* x    = (const float*)d_in[0];
  const int*   ei   = (const int*)d_in[1];
  const float* W_in = (const float*)d_in[2];
  const float* b_in = (const float*)d_in[3];
  const float* Wq   = (const float*)d_in[4];
  const float* bq   = (const float*)d_in[5];
  const float* Wk   = (const float*)d_in[6];
  const float* bk   = (const float*)d_in[7];
  const float* Wv   = (const float*)d_in[8];
  const float* bv   = (const float*)d_in[9];
  const float* Wsk  = (const float*)d_in[10];
  const float* bsk  = (const float*)d_in[11];
  const float* ln_g = (const float*)d_in[12];
  const float* ln_b = (const float*)d_in[13];
  const float* Wc   = (const float*)d_in[14];
  const float* bc   = (const float*)d_in[15];
  float* out = (float*)d_out;

  char* ws = (char*)d_ws;
  size_t off = 0;
  float*  hA    = (float*)(ws + off);  off += (size_t)NN * DD * 4;          // h0, later h2
  float*  hB    = (float*)(ws + off);  off += (size_t)NN * DD * 4;          // h1
  float*  qb    = (float*)(ws + off);  off += (size_t)NN * HHEADS * DD * 4;
  __bf16* kb    = (__bf16*)(ws + off); off += (size_t)NN * HHEADS * DD * 2;
  __bf16* vb    = (__bf16*)(ws + off); off += (size_t)NN * HHEADS * DD * 2;
  float*  skipb = (float*)(ws + off);  off += (size_t)NN * DD * 4;
  __bf16* hb0   = (__bf16*)(ws + off); off += (size_t)NN * DD * 2;
  __bf16* hb1   = (__bf16*)(ws + off); off += (size_t)NN * DD * 2;
  __bf16* xb    = (__bf16*)(ws + off); off += (size_t)NN * DIN * 2;
  __bf16* WT    = (__bf16*)(ws + off); off += (size_t)458752 * 2;
  int* deg      = (int*)(ws + off);    off += (size_t)NN * 4;
  int* cnt      = (int*)(ws + off);    off += (size_t)NN * 4;
  int* fillp    = (int*)(ws + off);    off += (size_t)NN * 4;
  int* row_ptr  = (int*)(ws + off);    off += (size_t)(NN + 1) * 4;
  int* ssrc     = (int*)(ws + off);    off += (size_t)EE * 4;

  __bf16* W_inT = WT;
  __bf16* WqT   = WT + 32768;
  __bf16* WkT   = WT + 163840;
  __bf16* WvT   = WT + 294912;
  __bf16* WskT  = WT + 425984;

  // zero deg+cnt (contiguous 2*NN ints) via plain kernel — no memset nodes in the graph
  zero_ints<<<(2 * NN + 255) / 256, 256, 0, stream>>>(deg, 2 * NN);

  count_kernel<<<(EE + 255) / 256, 256, 0, stream>>>(ei, deg, cnt);
  scan_kernel<<<1, 256, 0, stream>>>(cnt, row_ptr);
  copy_ints<<<(NN + 255) / 256, 256, 0, stream>>>(row_ptr, fillp, NN);
  scatter_kernel<<<(EE + 255) / 256, 256, 0, stream>>>(ei, fillp, ssrc);

  pack_weights<<<(458752 + 255) / 256, 256, 0, stream>>>(W_in, Wq, Wk, Wv, Wsk, WT);
  cvt_f32_bf16<<<((NN * DIN / 4) + 255) / 256, 256, 0, stream>>>(x, xb, NN * DIN / 4);

  // h0 = x @ W_in + b_in (MFMA, fp32 out) ; then += degree PE ; then bf16 copy
  {
    dim3 grid((NN + 63) / 64, DD / 64);
    mfma_gemm_bias<float><<<grid, 256, 0, stream>>>(xb, W_inT, b_in, hA, NN, DIN, DD);
  }
  add_pe_kernel<<<(NN * DD + 255) / 256, 256, 0, stream>>>(hA, deg);
  cvt_f32_bf16<<<((NN * DD / 4) + 255) / 256, 256, 0, stream>>>(hA, hb0, NN * DD / 4);

  // layer 0: reads hA/hb0 -> writes hB/hb1
  // layer 1: reads hB/hb1 -> writes hA/hb0 (hb0 is dead afterwards)
  const float*  h_in_l[2]  = {hA, hB};
  float*        h_out_l[2] = {hB, hA};
  const __bf16* hb_in_l[2] = {hb0, hb1};
  __bf16*       hb_out_l[2]= {hb1, hb0};

  for (int l = 0; l < 2; ++l) {
    dim3 gqkv((NN + 63) / 64, (HHEADS * DD) / 64);
    mfma_gemm_bias<float><<<gqkv, 256, 0, stream>>>(hb_in_l[l], WqT + (size_t)l * 65536,
        bq + (size_t)l * 512, qb, NN, DD, HHEADS * DD);
    mfma_gemm_bias<__bf16><<<gqkv, 256, 0, stream>>>(hb_in_l[l], WkT + (size_t)l * 65536,
        bk + (size_t)l * 512, kb, NN, DD, HHEADS * DD);
    mfma_gemm_bias<__bf16><<<gqkv, 256, 0, stream>>>(hb_in_l[l], WvT + (size_t)l * 65536,
        bv + (size_t)l * 512, vb, NN, DD, HHEADS * DD);
    dim3 gsk((NN + 63) / 64, DD / 64);
    mfma_gemm_bias<float><<<gsk, 256, 0, stream>>>(hb_in_l[l], WskT + (size_t)l * 16384,
        bsk + (size_t)l * 128, skipb, NN, DD, DD);

    attn_fused<<<NN, 256, 0, stream>>>(h_in_l[l], qb, kb, vb, skipb, row_ptr, ssrc,
                                       ln_g + (size_t)l * DD, ln_b + (size_t)l * DD,
                                       h_out_l[l], hb_out_l[l], (l == 0) ? 1 : 0);
  }

  out_gemm<<<NN / 4, 256, 0, stream>>>(hA, Wc, bc, out);
}

// Round 4
// 382.304 us; speedup vs baseline: 2.3228x; 1.3376x over previous
//
#include <hip/hip_runtime.h>
#include <math.h>

#define NN 20000
#define EE 320000
#define DIN 256
#define DD 128
#define HHEADS 4
#define NCLS 7

typedef __attribute__((ext_vector_type(8))) __bf16 bf16x8;
typedef __attribute__((ext_vector_type(4))) float f32x4;

__device__ __forceinline__ unsigned short f2bf(float f) {
  union { float f; unsigned int u; } c; c.f = f;
  unsigned int r = c.u + 0x7fffu + ((c.u >> 16) & 1u);  // RNE
  return (unsigned short)(r >> 16);
}
__device__ __forceinline__ __bf16 f2bf16(float f) {
  union { unsigned short u; __bf16 b; } cv; cv.u = f2bf(f); return cv.b;
}
__device__ __forceinline__ float bf_lo(unsigned int u) {
  union { unsigned int x; float f; } c; c.x = u << 16; return c.f;
}
__device__ __forceinline__ float bf_hi(unsigned int u) {
  union { unsigned int x; float f; } c; c.x = u & 0xffff0000u; return c.f;
}

// ---------------- utility ----------------
__global__ void zero_ints(int* __restrict__ p, int n) {
  int i = blockIdx.x * blockDim.x + threadIdx.x;
  if (i < n) p[i] = 0;
}
__global__ void copy_ints(const int* __restrict__ src, int* __restrict__ dst, int n) {
  int i = blockIdx.x * blockDim.x + threadIdx.x;
  if (i < n) dst[i] = src[i];
}

// ---------------- CSR build ----------------
__global__ void count_kernel(const int* __restrict__ ei, int* __restrict__ deg_src,
                             int* __restrict__ cnt_dst) {
  int e = blockIdx.x * blockDim.x + threadIdx.x;
  if (e >= EE) return;
  atomicAdd(&deg_src[ei[e]], 1);
  atomicAdd(&cnt_dst[ei[EE + e]], 1);
}

// 1024-thread single-block exclusive scan via wave shuffles
__global__ __launch_bounds__(1024) void scan_kernel(const int* __restrict__ cnt,
                                                    int* __restrict__ row_ptr) {
  __shared__ int wsum[16];
  __shared__ int carry_s;
  const int tid = threadIdx.x;
  const int wid = tid >> 6, lane = tid & 63;
  if (tid == 0) carry_s = 0;
  __syncthreads();
  for (int base = 0; base < NN; base += 1024) {
    int i = base + tid;
    int x = (i < NN) ? cnt[i] : 0;
    int v = x;
#pragma unroll
    for (int off = 1; off < 64; off <<= 1) {
      int t = __shfl_up(v, off);
      if (lane >= off) v += t;
    }
    if (lane == 63) wsum[wid] = v;
    __syncthreads();
    int woff = 0;
    for (int w = 0; w < wid; ++w) woff += wsum[w];
    int incl = carry_s + woff + v;
    if (i < NN) row_ptr[i] = incl - x;
    __syncthreads();
    if (tid == 1023) carry_s += woff + v;
    __syncthreads();
  }
  if (tid == 0) row_ptr[NN] = EE;
}

__global__ void scatter_kernel(const int* __restrict__ ei, int* __restrict__ fillp,
                               int* __restrict__ ssrc) {
  int e = blockIdx.x * blockDim.x + threadIdx.x;
  if (e >= EE) return;
  int s = ei[e], d = ei[EE + e];
  int pos = atomicAdd(&fillp[d], 1);
  ssrc[pos] = s;
}

// ---------------- pack weights ----------------
// WT (bf16 elements): W_inT[128][256] @0 | W2T[2][1664][128] @32768 | WcT[64][128] @458752
__global__ void pack_weights(const float* __restrict__ W_in, const float* __restrict__ Wq,
                             const float* __restrict__ Wk, const float* __restrict__ Wv,
                             const float* __restrict__ Wsk, const float* __restrict__ Wc,
                             __bf16* __restrict__ WT) {
  int idx = blockIdx.x * blockDim.x + threadIdx.x;
  if (idx >= 466944) return;
  float val;
  if (idx < 32768) {                       // W_inT: [m][k], m<128, k<256
    int m = idx >> 8, k = idx & 255;
    val = W_in[k * 128 + m];
  } else if (idx < 458752) {               // W2T: [l][r][kk]
    int t = idx - 32768;
    int l = t / 212992; int t2 = t - l * 212992;
    int r = t2 >> 7, kk = t2 & 127;
    if (r < 512)       val = Wq[l * 65536 + kk * 512 + r];
    else if (r < 1024) val = Wk[l * 65536 + kk * 512 + (r - 512)];
    else if (r < 1536) val = Wv[l * 65536 + kk * 512 + (r - 1024)];
    else               val = Wsk[l * 16384 + kk * 128 + (r - 1536)];
  } else {                                 // WcT: [r][kk], r<64 (pad), kk<128
    int t = idx - 458752;
    int r = t >> 7, kk = t & 127;
    val = (r < NCLS) ? Wc[kk * NCLS + r] : 0.f;
  }
  WT[idx] = f2bf16(val);
}

// bcomb[2][1664] | bcpad[64]
__global__ void pack_bias(const float* __restrict__ bq, const float* __restrict__ bk,
                          const float* __restrict__ bv, const float* __restrict__ bsk,
                          const float* __restrict__ bc, float* __restrict__ bcomb,
                          float* __restrict__ bcpad) {
  int idx = blockIdx.x * blockDim.x + threadIdx.x;
  if (idx < 3328) {
    int l = idx / 1664, r = idx % 1664;
    float v;
    if (r < 512)       v = bq[l * 512 + r];
    else if (r < 1024) v = bk[l * 512 + (r - 512)];
    else if (r < 1536) v = bv[l * 512 + (r - 1024)];
    else               v = bsk[l * 128 + (r - 1536)];
    bcomb[idx] = v;
  } else if (idx < 3392) {
    int r = idx - 3328;
    bcpad[r] = (r < NCLS) ? bc[r] : 0.f;
  }
}

__global__ void cvt_f32_bf16(const float* __restrict__ in, __bf16* __restrict__ out, int n4) {
  int i = blockIdx.x * blockDim.x + threadIdx.x;
  if (i >= n4) return;
  float4 f = reinterpret_cast<const float4*>(in)[i];
  ushort4 u;
  u.x = f2bf(f.x); u.y = f2bf(f.y); u.z = f2bf(f.z); u.w = f2bf(f.w);
  reinterpret_cast<ushort4*>(out)[i] = u;
}

// ---------------- MFMA GEMM, 3 epilogue modes ----------------
// MODE 0 (IN):  C = A@BT + bias + degree-PE -> p0 (fp32 [n][128]) and p1 (bf16 [n][128])
// MODE 1 (QKV): cols 0-511 -> p0 fp32 q[n][512]; 512-1023 -> p1 bf16 k; 1024-1535 -> p2 bf16 v;
//               1536-1663 -> p3 fp32 skip[n][128]
// MODE 2 (CLS): cols <7 -> p0 fp32 out[n][7]
template <int MODE>
__global__ __launch_bounds__(256) void mfma_gemm(
    const __bf16* __restrict__ A, const __bf16* __restrict__ BT,
    const float* __restrict__ bias,
    float* __restrict__ p0, __bf16* __restrict__ p1, __bf16* __restrict__ p2,
    float* __restrict__ p3, const int* __restrict__ deg,
    int nrows, int K) {
  __shared__ __attribute__((aligned(16))) __bf16 As[64][72];
  __shared__ __attribute__((aligned(16))) __bf16 Bs[64][72];
  const int tid = threadIdx.x;
  const int brow = blockIdx.x * 64;
  const int bcol = blockIdx.y * 64;
  const int wave = tid >> 6, lane = tid & 63;
  const int wm = wave & 1, wn = wave >> 1;
  const int r8 = tid >> 3;
  const int c8 = (tid & 7) * 8;
  const int lm = lane & 15, lk = (lane >> 4) * 8;
  f32x4 acc[2][2] = {};
  for (int k0 = 0; k0 < K; k0 += 64) {
#pragma unroll
    for (int half = 0; half < 2; ++half) {
      int row = brow + half * 32 + r8;
      uint4 av = make_uint4(0, 0, 0, 0);
      if (row < nrows) av = *reinterpret_cast<const uint4*>(A + (size_t)row * K + k0 + c8);
      *reinterpret_cast<uint4*>(&As[half * 32 + r8][c8]) = av;
      int col = bcol + half * 32 + r8;
      uint4 bv = *reinterpret_cast<const uint4*>(BT + (size_t)col * K + k0 + c8);
      *reinterpret_cast<uint4*>(&Bs[half * 32 + r8][c8]) = bv;
    }
    __syncthreads();
#pragma unroll
    for (int ks = 0; ks < 2; ++ks) {
      bf16x8 af[2], bfr[2];
#pragma unroll
      for (int i = 0; i < 2; ++i)
        af[i] = *reinterpret_cast<const bf16x8*>(&As[wm * 32 + i * 16 + lm][ks * 32 + lk]);
#pragma unroll
      for (int j = 0; j < 2; ++j)
        bfr[j] = *reinterpret_cast<const bf16x8*>(&Bs[wn * 32 + j * 16 + lm][ks * 32 + lk]);
#pragma unroll
      for (int i = 0; i < 2; ++i)
#pragma unroll
        for (int j = 0; j < 2; ++j)
          acc[i][j] = __builtin_amdgcn_mfma_f32_16x16x32_bf16(af[i], bfr[j], acc[i][j], 0, 0, 0);
    }
    __syncthreads();
  }
#pragma unroll
  for (int i = 0; i < 2; ++i) {
#pragma unroll
    for (int j = 0; j < 2; ++j) {
      int col = bcol + wn * 32 + j * 16 + lm;
      float bb = bias[col];
#pragma unroll
      for (int r = 0; r < 4; ++r) {
        int row = brow + wm * 32 + i * 16 + (lane >> 4) * 4 + r;
        if (row >= nrows) continue;
        float val = acc[i][j][r] + bb;
        if constexpr (MODE == 0) {
          float dg = (float)deg[row];
          float freq = dg * __expf(-0.07195578415606394f * (float)col);
          float pe = (col & 1) ? __cosf(freq) : __sinf(freq);
          val += pe;
          p0[(size_t)row * DD + col] = val;
          p1[(size_t)row * DD + col] = f2bf16(val);
        } else if constexpr (MODE == 1) {
          if (col < 512)       p0[(size_t)row * 512 + col] = val;
          else if (col < 1024) p1[(size_t)row * 512 + (col - 512)] = f2bf16(val);
          else if (col < 1536) p2[(size_t)row * 512 + (col - 1024)] = f2bf16(val);
          else                 p3[(size_t)row * DD + (col - 1536)] = val;
        } else {
          if (col < NCLS) p0[(size_t)row * NCLS + col] = val;
        }
      }
    }
  }
}

// ---------------- fused attention + head-mean + skip + residual + LN (+ReLU) ----------------
// block = dst node; wave = head; 4 groups of 16 lanes, each group one edge at a time;
// lane owns 8 dims (16B bf16 loads).
__global__ __launch_bounds__(256) void attn_fused(
    const float* __restrict__ h_in, const float* __restrict__ q,
    const __bf16* __restrict__ k, const __bf16* __restrict__ v,
    const float* __restrict__ skipb,
    const int* __restrict__ row_ptr, const int* __restrict__ ssrc,
    const float* __restrict__ ln_g, const float* __restrict__ ln_b,
    float* __restrict__ h_out, __bf16* __restrict__ hb_out, int relu_flag) {
  const int i = blockIdx.x;
  const int tid = threadIdx.x;
  const int hh = tid >> 6;
  const int lane = tid & 63;
  const int g = lane >> 4;
  const int l16 = lane & 15;
  const int e0 = row_ptr[i], e1 = row_ptr[i + 1];
  const float scale = 0.088388347648318447f;  // 1/sqrt(128)

  float qv[8];
  {
    const float4* qp = reinterpret_cast<const float4*>(q + (size_t)i * 512 + hh * 128 + l16 * 8);
    float4 q0 = qp[0], q1 = qp[1];
    qv[0] = q0.x; qv[1] = q0.y; qv[2] = q0.z; qv[3] = q0.w;
    qv[4] = q1.x; qv[5] = q1.y; qv[6] = q1.z; qv[7] = q1.w;
  }
  float m = -INFINITY, s = 0.f;
  float a[8] = {0.f, 0.f, 0.f, 0.f, 0.f, 0.f, 0.f, 0.f};

  int e = e0 + g;
  uint4 kw = make_uint4(0, 0, 0, 0), vw = make_uint4(0, 0, 0, 0);
  if (e < e1) {
    int j = ssrc[e];
    kw = *reinterpret_cast<const uint4*>(k + (size_t)j * 512 + hh * 128 + l16 * 8);
    vw = *reinterpret_cast<const uint4*>(v + (size_t)j * 512 + hh * 128 + l16 * 8);
  }
  while (e < e1) {
    int en = e + 4;
    uint4 kn = kw, vn = vw;
    if (en < e1) {
      int jn = ssrc[en];
      kn = *reinterpret_cast<const uint4*>(k + (size_t)jn * 512 + hh * 128 + l16 * 8);
      vn = *reinterpret_cast<const uint4*>(v + (size_t)jn * 512 + hh * 128 + l16 * 8);
    }
    float dot = qv[0] * bf_lo(kw.x);
    dot = fmaf(qv[1], bf_hi(kw.x), dot);
    dot = fmaf(qv[2], bf_lo(kw.y), dot);
    dot = fmaf(qv[3], bf_hi(kw.y), dot);
    dot = fmaf(qv[4], bf_lo(kw.z), dot);
    dot = fmaf(qv[5], bf_hi(kw.z), dot);
    dot = fmaf(qv[6], bf_lo(kw.w), dot);
    dot = fmaf(qv[7], bf_hi(kw.w), dot);
    dot += __shfl_xor(dot, 1);
    dot += __shfl_xor(dot, 2);
    dot += __shfl_xor(dot, 4);
    dot += __shfl_xor(dot, 8);
    float sc = dot * scale;
    if (sc > m) {  // rare: expected ~H(deg) times per group
      float c = __expf(m - sc);
      s *= c;
#pragma unroll
      for (int d = 0; d < 8; ++d) a[d] *= c;
      m = sc;
    }
    float w = __expf(sc - m);
    s += w;
    a[0] = fmaf(w, bf_lo(vw.x), a[0]);
    a[1] = fmaf(w, bf_hi(vw.x), a[1]);
    a[2] = fmaf(w, bf_lo(vw.y), a[2]);
    a[3] = fmaf(w, bf_hi(vw.y), a[3]);
    a[4] = fmaf(w, bf_lo(vw.z), a[4]);
    a[5] = fmaf(w, bf_hi(vw.z), a[5]);
    a[6] = fmaf(w, bf_lo(vw.w), a[6]);
    a[7] = fmaf(w, bf_hi(vw.w), a[7]);
    kw = kn; vw = vn; e = en;
  }
  // merge the 4 groups (lanes g*16+l16, l16 fixed, hold same dims)
  float m1 = fmaxf(m, __shfl_xor(m, 16));
  float m_all = fmaxf(m1, __shfl_xor(m1, 32));
  float cg = (m > -1e30f) ? __expf(m - m_all) : 0.f;
  float sg = s * cg;
  sg += __shfl_xor(sg, 16);
  sg += __shfl_xor(sg, 32);
  float inv = 1.f / (sg + 1e-16f);

  __shared__ float agg[HHEADS][DD];
  __shared__ float red[8];
#pragma unroll
  for (int d = 0; d < 8; ++d) {
    float ad = a[d] * cg;
    ad += __shfl_xor(ad, 16);
    ad += __shfl_xor(ad, 32);
    a[d] = ad * inv;
  }
  if (g == 0) {
#pragma unroll
    for (int d = 0; d < 8; ++d) agg[hh][l16 * 8 + d] = a[d];
  }
  __syncthreads();

  float val = 0.f;
  const int d = tid;
  if (tid < DD) {
    float hmean = (agg[0][d] + agg[1][d] + agg[2][d] + agg[3][d]) * 0.25f;
    val = hmean + skipb[(size_t)i * DD + d] + h_in[(size_t)i * DD + d];
  }
  float sum = (tid < DD) ? val : 0.f;
  float sq = (tid < DD) ? val * val : 0.f;
#pragma unroll
  for (int off = 32; off; off >>= 1) {
    sum += __shfl_xor(sum, off);
    sq += __shfl_xor(sq, off);
  }
  if (lane == 0) { red[hh] = sum; red[4 + hh] = sq; }
  __syncthreads();
  float tot = red[0] + red[1] + red[2] + red[3];
  float tot2 = red[4] + red[5] + red[6] + red[7];
  float mu = tot * (1.f / 128.f);
  float var = tot2 * (1.f / 128.f) - mu * mu;
  float rstd = rsqrtf(var + 1e-5f);
  if (tid < DD) {
    float y = (val - mu) * rstd * ln_g[d] + ln_b[d];
    if (relu_flag) y = fmaxf(y, 0.f);
    h_out[(size_t)i * DD + d] = y;
    hb_out[(size_t)i * DD + d] = f2bf16(y);
  }
}

extern "C" void kernel_launch(void* const* d_in, const int* in_sizes, int n_in,
                              void* d_out, int out_size, void* d_ws, size_t ws_size,
                              hipStream_t stream) {
  const float* x    = (const float*)d_in[0];
  const int*   ei   = (const int*)d_in[1];
  const float* W_in = (const float*)d_in[2];
  const float* b_in = (const float*)d_in[3];
  const float* Wq   = (const float*)d_in[4];
  const float* bq   = (const float*)d_in[5];
  const float* Wk   = (const float*)d_in[6];
  const float* bk   = (const float*)d_in[7];
  const float* Wv   = (const float*)d_in[8];
  const float* bv   = (const float*)d_in[9];
  const float* Wsk  = (const float*)d_in[10];
  const float* bsk  = (const float*)d_in[11];
  const float* ln_g = (const float*)d_in[12];
  const float* ln_b = (const float*)d_in[13];
  const float* Wc   = (const float*)d_in[14];
  const float* bc   = (const float*)d_in[15];
  float* out = (float*)d_out;

  char* ws = (char*)d_ws;
  size_t off = 0;
  float*  hA    = (float*)(ws + off);  off += (size_t)NN * DD * 4;
  float*  hB    = (float*)(ws + off);  off += (size_t)NN * DD * 4;
  float*  qb    = (float*)(ws + off);  off += (size_t)NN * 512 * 4;
  __bf16* kb    = (__bf16*)(ws + off); off += (size_t)NN * 512 * 2;
  __bf16* vb    = (__bf16*)(ws + off); off += (size_t)NN * 512 * 2;
  float*  skipb = (float*)(ws + off);  off += (size_t)NN * DD * 4;
  __bf16* hb0   = (__bf16*)(ws + off); off += (size_t)NN * DD * 2;
  __bf16* hb1   = (__bf16*)(ws + off); off += (size_t)NN * DD * 2;
  __bf16* xb    = (__bf16*)(ws + off); off += (size_t)NN * DIN * 2;
  __bf16* WT    = (__bf16*)(ws + off); off += (size_t)466944 * 2;
  float*  bcomb = (float*)(ws + off);  off += (size_t)3328 * 4;
  float*  bcpad = (float*)(ws + off);  off += (size_t)64 * 4;
  int* deg      = (int*)(ws + off);    off += (size_t)NN * 4;
  int* cnt      = (int*)(ws + off);    off += (size_t)NN * 4;
  int* fillp    = (int*)(ws + off);    off += (size_t)NN * 4;
  int* row_ptr  = (int*)(ws + off);    off += (size_t)(NN + 1) * 4;
  int* ssrc     = (int*)(ws + off);    off += (size_t)EE * 4;

  __bf16* W_inT = WT;
  __bf16* W2T   = WT + 32768;
  __bf16* WcT   = WT + 458752;

  zero_ints<<<(2 * NN + 255) / 256, 256, 0, stream>>>(deg, 2 * NN);
  count_kernel<<<(EE + 255) / 256, 256, 0, stream>>>(ei, deg, cnt);
  scan_kernel<<<1, 1024, 0, stream>>>(cnt, row_ptr);
  copy_ints<<<(NN + 255) / 256, 256, 0, stream>>>(row_ptr, fillp, NN);
  scatter_kernel<<<(EE + 255) / 256, 256, 0, stream>>>(ei, fillp, ssrc);

  pack_weights<<<(466944 + 255) / 256, 256, 0, stream>>>(W_in, Wq, Wk, Wv, Wsk, Wc, WT);
  pack_bias<<<(3392 + 255) / 256, 256, 0, stream>>>(bq, bk, bv, bsk, bc, bcomb, bcpad);
  cvt_f32_bf16<<<((NN * DIN / 4) + 255) / 256, 256, 0, stream>>>(x, xb, NN * DIN / 4);

  // h0 = x @ W_in + b_in + PE  -> hA (fp32) + hb0 (bf16), fused epilogue
  {
    dim3 grid((NN + 63) / 64, 2);
    mfma_gemm<0><<<grid, 256, 0, stream>>>(xb, W_inT, b_in, hA, hb0, nullptr, nullptr,
                                           deg, NN, DIN);
  }

  const float*  h_in_l[2]   = {hA, hB};
  float*        h_out_l[2]  = {hB, hA};
  const __bf16* hb_in_l[2]  = {hb0, hb1};
  __bf16*       hb_out_l[2] = {hb1, hb0};

  for (int l = 0; l < 2; ++l) {
    dim3 gqkv((NN + 63) / 64, 26);  // 1664 cols
    mfma_gemm<1><<<gqkv, 256, 0, stream>>>(hb_in_l[l], W2T + (size_t)l * 212992,
                                           bcomb + (size_t)l * 1664,
                                           qb, kb, vb, skipb, nullptr, NN, DD);
    attn_fused<<<NN, 256, 0, stream>>>(h_in_l[l], qb, kb, vb, skipb, row_ptr, ssrc,
                                       ln_g + (size_t)l * DD, ln_b + (size_t)l * DD,
                                       h_out_l[l], hb_out_l[l], (l == 0) ? 1 : 0);
  }

  // classifier: out = h @ Wc + bc  (A = hb0, final bf16 h)
  {
    dim3 gcls((NN + 63) / 64, 1);
    mfma_gemm<2><<<gcls, 256, 0, stream>>>(hb0, WcT, bcpad, out, nullptr, nullptr, nullptr,
                                           nullptr, NN, DD);
  }
}